// Round 6
// baseline (844.594 us; speedup 1.0000x reference)
//
#include <hip/hip_runtime.h>
#include <cstdint>

#define NPTS 8192
#define NB 8
#define DS 512
#define CF 64
#define KNN 32

// ---- DPP wave-64 reductions (VALU only, no DS pipe) ----------------------
// row_shr 1/2/4/8 + row_bcast15/31: full wave-64 max accumulates in lane 63.
// bound_ctrl=1 zero-fill is identity-safe for max of non-negative values.
__device__ __forceinline__ float wave_max63(float x) {
  int v;
  v = __builtin_amdgcn_update_dpp(0, __float_as_int(x), 0x111, 0xf, 0xf, true); x = fmaxf(x, __int_as_float(v));
  v = __builtin_amdgcn_update_dpp(0, __float_as_int(x), 0x112, 0xf, 0xf, true); x = fmaxf(x, __int_as_float(v));
  v = __builtin_amdgcn_update_dpp(0, __float_as_int(x), 0x114, 0xf, 0xf, true); x = fmaxf(x, __int_as_float(v));
  v = __builtin_amdgcn_update_dpp(0, __float_as_int(x), 0x118, 0xf, 0xf, true); x = fmaxf(x, __int_as_float(v));
  v = __builtin_amdgcn_update_dpp(0, __float_as_int(x), 0x142, 0xf, 0xf, true); x = fmaxf(x, __int_as_float(v));
  v = __builtin_amdgcn_update_dpp(0, __float_as_int(x), 0x143, 0xf, 0xf, true); x = fmaxf(x, __int_as_float(v));
  return x;  // valid in lane 63
}

__device__ __forceinline__ float wave_sum_bcast(float x) {
  int v;
  v = __builtin_amdgcn_update_dpp(0, __float_as_int(x), 0x111, 0xf, 0xf, true); x += __int_as_float(v);
  v = __builtin_amdgcn_update_dpp(0, __float_as_int(x), 0x112, 0xf, 0xf, true); x += __int_as_float(v);
  v = __builtin_amdgcn_update_dpp(0, __float_as_int(x), 0x114, 0xf, 0xf, true); x += __int_as_float(v);
  v = __builtin_amdgcn_update_dpp(0, __float_as_int(x), 0x118, 0xf, 0xf, true); x += __int_as_float(v);
  v = __builtin_amdgcn_update_dpp(0, __float_as_int(x), 0x142, 0xf, 0xf, true); x += __int_as_float(v);
  v = __builtin_amdgcn_update_dpp(0, __float_as_int(x), 0x143, 0xf, 0xf, true); x += __int_as_float(v);
  return __int_as_float(__builtin_amdgcn_readlane(__float_as_int(x), 63));
}

__device__ __forceinline__ int part3b(int v) {  // 3 bits -> bits 0,3,6
  return (v & 1) | ((v & 2) << 2) | ((v & 4) << 4);
}

__global__ __launch_bounds__(64) void zero_kernel(float* __restrict__ acc) {
  if (threadIdx.x < 16) acc[threadIdx.x] = 0.0f;
}

// blocks 0..15: FPS (view=blk>>3, batch=blk&7). blocks 16..79: global cosine.
// FPS: Morton counting-sort -> 16 waves own compact spatial regions (512 pts
// each, coords+dists in regs). Per iter a wave skips its whole update when
// d(w,bbox)^2*(1-1e-6) > wave_max_dist (conservative-exact: min() provably
// unchanged). Winner coords come from the winner thread's registers.
__global__ __launch_bounds__(1024, 4) void fps_cos_kernel(
    const float* __restrict__ logits, const float* __restrict__ logits1,
    const float* __restrict__ p0first, const float* __restrict__ p0sec,
    int* __restrict__ idxbuf, float* __restrict__ acc) {
  __shared__ float4 spts[NPTS];       // sorted {x,y,z,asfloat(origidx)} 128 KB
  __shared__ int cellcnt[512];
  __shared__ int cellstart[512];
  __shared__ int cellslot[512];
  __shared__ __align__(16) float wmax16[16];
  __shared__ unsigned long long winkey[2];
  __shared__ float4 winpt;
  __shared__ float s_sum;
  const int blk = blockIdx.x;
  const int t = threadIdx.x;
  if (blk < 16) {
    const int view = blk >> 3, b = blk & 7;
    const float* p = (view ? p0sec : p0first) + (size_t)b * NPTS * 3;
    int* idx_out = idxbuf + blk * DS;
    const int lane = t & 63, wave = t >> 6;  // 16 waves
    // ---- S1: load 8 pts/thread, Morton cell, count --------------------
    float tx[8], ty[8], tz[8];
    int tc[8];
    for (int i = t; i < 512; i += 1024) cellcnt[i] = 0;
    __syncthreads();
#pragma unroll
    for (int k = 0; k < 8; ++k) {
      int e = k * 1024 + t;
      tx[k] = p[e * 3 + 0]; ty[k] = p[e * 3 + 1]; tz[k] = p[e * 3 + 2];
      int ix = (int)(tx[k] * 8.0f); ix = ix < 0 ? 0 : (ix > 7 ? 7 : ix);
      int iy = (int)(ty[k] * 8.0f); iy = iy < 0 ? 0 : (iy > 7 ? 7 : iy);
      int iz = (int)(tz[k] * 8.0f); iz = iz < 0 ? 0 : (iz > 7 ? 7 : iz);
      tc[k] = part3b(ix) | (part3b(iy) << 1) | (part3b(iz) << 2);
      atomicAdd(&cellcnt[tc[k]], 1);
    }
    __syncthreads();
    // ---- S2: exclusive scan of 512 cell counts (wave 0) ---------------
    if (t < 64) {
      int c0[8]; int tot = 0;
#pragma unroll
      for (int i = 0; i < 8; ++i) { c0[i] = cellcnt[t * 8 + i]; tot += c0[i]; }
      int inc = tot;
#pragma unroll
      for (int o = 1; o < 64; o <<= 1) {
        int v = __shfl_up(inc, o, 64);
        if (t >= o) inc += v;
      }
      int run = inc - tot;
#pragma unroll
      for (int i = 0; i < 8; ++i) { cellstart[t * 8 + i] = run; run += c0[i]; }
    }
    __syncthreads();
    // ---- S3: scatter into Morton-sorted order -------------------------
    if (t < 512) cellslot[t] = cellstart[t];
    __syncthreads();
#pragma unroll
    for (int k = 0; k < 8; ++k) {
      int pos = atomicAdd(&cellslot[tc[k]], 1);
      spts[pos] = make_float4(tx[k], ty[k], tz[k], __int_as_float(k * 1024 + t));
    }
    __syncthreads();
    // ---- S4: each wave owns sorted range [wave*512, wave*512+512) -----
    float px[8], py[8], pz[8], dist[8];
    int oi[8];
#pragma unroll
    for (int k = 0; k < 8; ++k) {
      float4 f4 = spts[wave * 512 + lane + k * 64];
      px[k] = f4.x; py[k] = f4.y; pz[k] = f4.z;
      oi[k] = __float_as_int(f4.w);
      dist[k] = 3.4e38f;
      asm("" : "+v"(px[k]), "+v"(py[k]), "+v"(pz[k]), "+v"(oi[k]));  // no remat
    }
    // ---- S5: wave bbox (butterfly, setup-only) ------------------------
    float lox = px[0], hix = px[0], loy = py[0], hiy = py[0], loz = pz[0], hiz = pz[0];
#pragma unroll
    for (int k = 1; k < 8; ++k) {
      lox = fminf(lox, px[k]); hix = fmaxf(hix, px[k]);
      loy = fminf(loy, py[k]); hiy = fmaxf(hiy, py[k]);
      loz = fminf(loz, pz[k]); hiz = fmaxf(hiz, pz[k]);
    }
#pragma unroll
    for (int o = 1; o < 64; o <<= 1) {
      lox = fminf(lox, __shfl_xor(lox, o, 64)); hix = fmaxf(hix, __shfl_xor(hix, o, 64));
      loy = fminf(loy, __shfl_xor(loy, o, 64)); hiy = fmaxf(hiy, __shfl_xor(hiy, o, 64));
      loz = fminf(loz, __shfl_xor(loz, o, 64)); hiz = fmaxf(hiz, __shfl_xor(hiz, o, 64));
    }
    if (t == 0) {
      idx_out[0] = 0;
      winkey[0] = 0ull; winkey[1] = 0ull;
    }
    float wx = p[0], wy = p[1], wz = p[2];  // seed = point 0
    float wavemax_c = 3.4e38f;              // cached wave max (uniform)
    float lm = -1.0f;                       // per-thread max dist (persistent)
    __syncthreads();
    for (int it = 0; it < DS - 1; ++it) {
      // A: conservative wave-skip test (wave-uniform branch)
      float dxl = fmaxf(fmaxf(lox - wx, wx - hix), 0.0f);
      float dyl = fmaxf(fmaxf(loy - wy, wy - hiy), 0.0f);
      float dzl = fmaxf(fmaxf(loz - wz, wz - hiz), 0.0f);
      float bd2 = dxl * dxl + dyl * dyl + dzl * dzl;
      if (!(bd2 * 0.999999f > wavemax_c)) {  // active
        float lmn = -1.0f;
#pragma unroll
        for (int k = 0; k < 8; ++k) {
          float dx = px[k] - wx, dy = py[k] - wy, dz = pz[k] - wz;
          float nd = dx * dx + dy * dy + dz * dz;
          float d = fminf(dist[k], nd);
          dist[k] = d;
          lmn = fmaxf(lmn, d);
        }
        lm = lmn;
        float wm = wave_max63(lm);
        if (lane == 63) wmax16[wave] = wm;
        wavemax_c = __int_as_float(__builtin_amdgcn_readlane(__float_as_int(wm), 63));
      }
      // skipped waves: wmax16[wave] still holds wavemax_c from last active iter
      __syncthreads();  // bar1
      if (t == 0) winkey[(it + 1) & 1] = 0ull;  // safe: slot untouched this iter
      // C: block max of the 16 wave maxes (broadcast b128 reads)
      float4 q0 = *(const float4*)&wmax16[0];
      float4 q1 = *(const float4*)&wmax16[4];
      float4 q2 = *(const float4*)&wmax16[8];
      float4 q3 = *(const float4*)&wmax16[12];
      float g01 = fmaxf(fmaxf(q0.x, q0.y), fmaxf(q0.z, q0.w));
      float g23 = fmaxf(fmaxf(q1.x, q1.y), fmaxf(q1.z, q1.w));
      float g45 = fmaxf(fmaxf(q2.x, q2.y), fmaxf(q2.z, q2.w));
      float g67 = fmaxf(fmaxf(q3.x, q3.y), fmaxf(q3.z, q3.w));
      float gmax = fmaxf(fmaxf(g01, g23), fmaxf(g45, g67));
      // D: threads holding the block max resolve argmax (exact jnp tie-break)
      unsigned long long mykey = 0ull;
      int kb = 0;
      if (lm == gmax) {
        int besto = 0x7fffffff;
#pragma unroll
        for (int k = 7; k >= 0; --k)
          if (dist[k] == lm && oi[k] < besto) { besto = oi[k]; kb = k; }
        mykey = (((unsigned long long)__float_as_uint(lm)) << 32) |
                (unsigned)(8191 - besto);
        atomicMax(&winkey[it & 1], mykey);
      }
      __syncthreads();  // bar2
      // E: unique winner publishes its coords from registers
      unsigned long long kk = winkey[it & 1];
      if (mykey == kk && lm == gmax) {
        float bx = px[0], by = py[0], bz = pz[0];
#pragma unroll
        for (int k = 1; k < 8; ++k)
          if (kb == k) { bx = px[k]; by = py[k]; bz = pz[k]; }
        winpt = make_float4(bx, by, bz, 0.0f);
      }
      if (t == 0) idx_out[it + 1] = (int)(8191u - (unsigned)(kk & 0xffffffffu));
      __syncthreads();  // bar3
      float4 wv = winpt;
      wx = wv.x; wy = wv.y; wz = wv.z;
    }
  } else {
    // global per-point cosine loss: one thread per row of 64
    if (t == 0) s_sum = 0.0f;
    __syncthreads();
    const int row = (blk - 16) * 1024 + t;  // 0..65535
    const float4* A = (const float4*)(logits + (size_t)row * CF);
    const float4* Bv = (const float4*)(logits1 + (size_t)row * CF);
    float ab = 0.f, aa = 0.f, bb = 0.f;
#pragma unroll
    for (int i = 0; i < 16; ++i) {
      float4 a = A[i], c = Bv[i];
      ab += a.x * c.x + a.y * c.y + a.z * c.z + a.w * c.w;
      aa += a.x * a.x + a.y * a.y + a.z * a.z + a.w * a.w;
      bb += c.x * c.x + c.y * c.y + c.z * c.z + c.w * c.w;
    }
    float cv = ab / fmaxf(sqrtf(aa) * sqrtf(bb), 1e-8f);
    cv = wave_sum_bcast(cv);
    if ((t & 63) == 0) atomicAdd(&s_sum, cv);
    __syncthreads();
    if (t == 0) atomicAdd(&acc[0], s_sum);
  }
}

// scan lane-group-replicated 256-bin histograms, pick bin containing rrank
__device__ __forceinline__ void radix_scan8(int (*hist)[264], int rrank, int* s_bl, int t) {
  if (t < 64) {
    int h0 = 0, h1 = 0, h2 = 0, h3 = 0;
#pragma unroll
    for (int c = 0; c < 8; ++c) {
      h0 += hist[c][t * 4 + 0]; h1 += hist[c][t * 4 + 1];
      h2 += hist[c][t * 4 + 2]; h3 += hist[c][t * 4 + 3];
    }
    int s = h0 + h1 + h2 + h3;
    int inc = s;
#pragma unroll
    for (int o = 1; o < 64; o <<= 1) {
      int v = __shfl_up(inc, o, 64);
      if (t >= o) inc += v;
    }
    int exc = inc - s;
    bool has = (rrank >= exc) && (rrank < inc);
    unsigned long long mask = __ballot(has);
    int win = __ffsll(mask) - 1;
    int wexc = __shfl(exc, win, 64);
    int wh0 = __shfl(h0, win, 64), wh1 = __shfl(h1, win, 64);
    int wh2 = __shfl(h2, win, 64);
    int r2 = rrank - wexc;
    int bin, less;
    if (r2 < wh0) { bin = 0; less = 0; }
    else if (r2 < wh0 + wh1) { bin = 1; less = wh0; }
    else if (r2 < wh0 + wh1 + wh2) { bin = 2; less = wh0 + wh1; }
    else { bin = 3; less = wh0 + wh1 + wh2; }
    if (t == 0) { s_bl[0] = win * 4 + bin; s_bl[1] = wexc + less; }
  }
  __syncthreads();
}

// one block (256 thr) per query; exact top-32 set via 4-pass radix select.
__global__ __launch_bounds__(256) void knn_kernel(
    const float* __restrict__ p0first, const float* __restrict__ p0sec,
    const int* __restrict__ idxbuf, int* __restrict__ knnbuf) {
  __shared__ int hist[8][264];
  __shared__ int s_bl[2];
  __shared__ int ctr, eqctr;
  __shared__ int eq[256];
  const int g = blockIdx.x;  // 0..8191 : view*4096 + b*512 + m
  const int t = threadIdx.x;
  const int c = t & 7;
  const int view = g >> 12, b = (g >> 9) & 7;
  const float* p = (view ? p0sec : p0first) + (size_t)b * NPTS * 3;
  const int qi = idxbuf[g];
  const float qx = p[qi * 3], qy = p[qi * 3 + 1], qz = p[qi * 3 + 2];
  const float qq = qx * qx + qy * qy + qz * qz;
  unsigned sk[32];
#pragma unroll
  for (int j = 0; j < 32; ++j) {
    int e = j * 256 + t;
    float sx = p[e * 3], sy = p[e * 3 + 1], sz = p[e * 3 + 2];
    float ss = sx * sx + sy * sy + sz * sz;
    float dt = qx * sx + qy * sy + qz * sz;
    float d = qq + ss - 2.0f * dt;  // same formula as reference
    unsigned u = __float_as_uint(d);
    u = (u & 0x80000000u) ? ~u : (u | 0x80000000u);  // sortable
    sk[j] = u;
  }
  int rrank = 31;  // 0-indexed rank of 32nd smallest
  unsigned prefix = 0;
  // pass 0
  for (int k = t; k < 8 * 264; k += 256) ((int*)hist)[k] = 0;
  __syncthreads();
#pragma unroll
  for (int j = 0; j < 32; ++j) atomicAdd(&hist[c][sk[j] >> 24], 1);
  __syncthreads();
  radix_scan8(hist, rrank, s_bl, t);
  prefix = (unsigned)s_bl[0];
  rrank -= s_bl[1];
  // passes 1..3
  for (int pass = 1; pass < 4; ++pass) {
    const int shift = 24 - pass * 8;
    for (int k = t; k < 8 * 264; k += 256) ((int*)hist)[k] = 0;
    __syncthreads();
#pragma unroll
    for (int j = 0; j < 32; ++j) {
      unsigned u = sk[j];
      if ((u >> (shift + 8)) == prefix) atomicAdd(&hist[c][(u >> shift) & 255], 1);
    }
    __syncthreads();
    radix_scan8(hist, rrank, s_bl, t);
    prefix = (prefix << 8) | (unsigned)s_bl[0];
    rrank -= s_bl[1];
  }
  // output: all keys < V, plus (rrank+1) smallest-index keys == V. Order irrelevant.
  if (t == 0) { ctr = 0; eqctr = 0; }
  __syncthreads();
  const unsigned V = prefix;
  int* out = knnbuf + (size_t)g * KNN;
#pragma unroll
  for (int j = 0; j < 32; ++j) {
    unsigned u = sk[j];
    if (u < V) {
      int s = atomicAdd(&ctr, 1);
      out[s] = j * 256 + t;
    } else if (u == V) {
      int s2 = atomicAdd(&eqctr, 1);
      if (s2 < 256) eq[s2] = j * 256 + t;
    }
  }
  __syncthreads();
  if (t == 0) {
    int need = rrank + 1;
    int E = eqctr; if (E > 256) E = 256;
    int base = 32 - need;
    for (int s = 0; s < need; ++s) {
      int mi = 0;
      for (int i = 1; i < E; ++i)
        if (eq[i] < eq[mi]) mi = i;
      out[base + s] = eq[mi];
      eq[mi] = 0x7fffffff;
    }
  }
}

// one wave per group (lane = feature dim); 4 groups per block; DPP reductions
__global__ __launch_bounds__(256) void group_kernel(
    const float* __restrict__ logits, const float* __restrict__ logits1,
    const int* __restrict__ idxbuf, const int* __restrict__ knnbuf,
    float* __restrict__ acc) {
  __shared__ float ws4[4];
  const int w = threadIdx.x >> 6, lane = threadIdx.x & 63;
  const int wid = blockIdx.x * 4 + w;  // 0..8191
  const int view = wid >> 12, b = (wid >> 9) & 7;
  const float* f = (view ? logits1 : logits) + (size_t)b * NPTS * CF;
  const int* nb = knnbuf + (size_t)wid * KNN;
  const int ci = idxbuf[wid];
  float r[33];
  float avg = 0.0f;
#pragma unroll
  for (int j = 0; j < 33; ++j) {
    int e = (j < 32) ? nb[j] : ci;
    float v = f[(size_t)e * CF + lane];
    r[j] = v;
    avg += v;
  }
  avg *= (1.0f / 33.0f);
  float na = wave_sum_bcast(avg * avg);
  const float rsna = sqrtf(na);
  float loss = 0.0f;
#pragma unroll
  for (int j = 0; j < 33; ++j) {
    float d0 = wave_sum_bcast(r[j] * avg);
    float n0 = wave_sum_bcast(r[j] * r[j]);
    float den = fmaxf(sqrtf(n0) * rsna, 1e-8f);
    loss += -200.0f * (d0 / den) - 0.5f * log1pf(40.0f * n0);
  }
  loss *= (1.0f / 33.0f);
  if (lane == 0) ws4[w] = loss;
  __syncthreads();
  if (threadIdx.x == 0) atomicAdd(&acc[1 + b], ws4[0] + ws4[1] + ws4[2] + ws4[3]);
}

__global__ __launch_bounds__(64) void finalize_kernel(const float* __restrict__ acc,
                                                      float* __restrict__ out) {
  if (threadIdx.x == 0 && blockIdx.x == 0) {
    float gl = -acc[0] / 65536.0f;
    float g = 0.0f;
    for (int b = 0; b < 8; ++b) g = (g + acc[1 + b]) * (1.0f / 512.0f);
    g *= 0.125f;  // / b
    out[0] = gl + g + g;
  }
}

extern "C" void kernel_launch(void* const* d_in, const int* in_sizes, int n_in,
                              void* d_out, int out_size, void* d_ws, size_t ws_size,
                              hipStream_t stream) {
  (void)in_sizes; (void)n_in; (void)out_size; (void)ws_size;
  const float* logits  = (const float*)d_in[0];
  const float* logits1 = (const float*)d_in[1];
  const float* p0first = (const float*)d_in[2];
  const float* p0sec   = (const float*)d_in[3];
  float* out = (float*)d_out;

  float* acc = (float*)d_ws;                 // [0]=cosSum, [1..8]=S[b]
  int* idxbuf = (int*)d_ws + 16;             // [2*8*512]
  int* knnbuf = idxbuf + 2 * NB * DS;        // [2*8*512*32]

  zero_kernel<<<1, 64, 0, stream>>>(acc);
  fps_cos_kernel<<<16 + 64, 1024, 0, stream>>>(logits, logits1, p0first, p0sec, idxbuf, acc);
  knn_kernel<<<2 * NB * DS, 256, 0, stream>>>(p0first, p0sec, idxbuf, knnbuf);
  group_kernel<<<2 * NB * DS / 4, 256, 0, stream>>>(logits, logits1, idxbuf, knnbuf, acc);
  finalize_kernel<<<1, 64, 0, stream>>>(acc, out);
}